// Round 6
// baseline (306.447 us; speedup 1.0000x reference)
//
#include <hip/hip_runtime.h>
#include <hip/hip_bf16.h>

#define B_ 4
#define S_ 2048
#define E_ 1024
#define H_ 16
#define D_ 64
#define QSCALE 0.18033688011112042f  // (1/8) * log2(e) : softmax in exp2 domain

typedef __attribute__((ext_vector_type(8))) short bf16x8;   // 8 bf16 (4 VGPRs)
typedef __attribute__((ext_vector_type(4))) float f32x4;    // 16x16 C/D frag
typedef __attribute__((ext_vector_type(16))) float f32x16;  // 32x32 C/D frag

__device__ __forceinline__ f32x4 mfma16(bf16x8 a, bf16x8 b, f32x4 c) {
    return __builtin_amdgcn_mfma_f32_16x16x32_bf16(a, b, c, 0, 0, 0);
}
__device__ __forceinline__ f32x16 mfma32(bf16x8 a, bf16x8 b, f32x16 c) {
    return __builtin_amdgcn_mfma_f32_32x32x16_bf16(a, b, c, 0, 0, 0);
}
__device__ __forceinline__ short f2bs(float f) {
    __hip_bfloat16 h = __float2bfloat16(f);
    return *reinterpret_cast<short*>(&h);
}

// slab strides (shorts): slab-to-slab offset == 4 banks mod 32 -> conflict-light
#define WSLAB 1544   // 192 rows * 8 + 8 pad
#define BSLAB 1032   // 128 rows * 8 + 8 pad

// ---------------------------------------------------------------------------
// x fp32 -> bf16 (one-time)
// ---------------------------------------------------------------------------
__global__ __launch_bounds__(256) void conv_x(
    const float* __restrict__ x, short* __restrict__ xb)
{
    const size_t i = ((size_t)blockIdx.x * 256 + threadIdx.x) * 8;
    const float4 v0 = *(const float4*)&x[i];
    const float4 v1 = *(const float4*)&x[i + 4];
    bf16x8 pk;
    pk[0] = f2bs(v0.x); pk[1] = f2bs(v0.y); pk[2] = f2bs(v0.z); pk[3] = f2bs(v0.w);
    pk[4] = f2bs(v1.x); pk[5] = f2bs(v1.y); pk[6] = f2bs(v1.z); pk[7] = f2bs(v1.w);
    *(bf16x8*)&xb[i] = pk;
}

// ---------------------------------------------------------------------------
// Transpose-convert Wq/Wk/Wv (per head [1024][64] fp32) -> WT[48][64][1024] bf16
// ---------------------------------------------------------------------------
__global__ __launch_bounds__(256) void conv_wqkv(
    const float* __restrict__ Wq, const float* __restrict__ Wk,
    const float* __restrict__ Wv, short* __restrict__ WT)
{
    const int mat = blockIdx.x >> 4;
    const int kt  = blockIdx.x & 15;
    const int which = mat >> 4, h = mat & 15;
    const float* src = (which == 0 ? Wq : which == 1 ? Wk : Wv) + (size_t)h * E_ * D_;
    __shared__ float T[64][65];
    const int tid = threadIdx.x;
    const int k0 = kt * 64;
    #pragma unroll
    for (int it = 0; it < 4; ++it) {
        int lin = tid + it * 256;
        int kr = lin >> 4, dc = (lin & 15) * 4;
        const float4 v = *(const float4*)&src[(size_t)(k0 + kr) * D_ + dc];
        T[kr][dc] = v.x; T[kr][dc + 1] = v.y; T[kr][dc + 2] = v.z; T[kr][dc + 3] = v.w;
    }
    __syncthreads();
    #pragma unroll
    for (int it = 0; it < 4; ++it) {
        int lin = tid + it * 256;
        int dr = lin >> 4, kc = (lin & 15) * 4;
        ushort4 o;
        o.x = (unsigned short)f2bs(T[kc][dr]);
        o.y = (unsigned short)f2bs(T[kc + 1][dr]);
        o.z = (unsigned short)f2bs(T[kc + 2][dr]);
        o.w = (unsigned short)f2bs(T[kc + 3][dr]);
        *(ushort4*)&WT[((size_t)mat * 64 + dr) * E_ + k0 + kc] = o;
    }
}

// ---------------------------------------------------------------------------
// Transpose-convert Wp [1024][1024] fp32 -> WpT[n][k] bf16
// ---------------------------------------------------------------------------
__global__ __launch_bounds__(256) void conv_wp(
    const float* __restrict__ Wp, short* __restrict__ WpT)
{
    const int ktile = blockIdx.x & 15, ntile = blockIdx.x >> 4;
    const int k0 = ktile * 64, n0 = ntile * 64;
    __shared__ float T[64][65];
    const int tid = threadIdx.x;
    #pragma unroll
    for (int it = 0; it < 4; ++it) {
        int lin = tid + it * 256;
        int kr = lin >> 4, nc = (lin & 15) * 4;
        const float4 v = *(const float4*)&Wp[(size_t)(k0 + kr) * E_ + n0 + nc];
        T[kr][nc] = v.x; T[kr][nc + 1] = v.y; T[kr][nc + 2] = v.z; T[kr][nc + 3] = v.w;
    }
    __syncthreads();
    #pragma unroll
    for (int it = 0; it < 4; ++it) {
        int lin = tid + it * 256;
        int nr = lin >> 4, kc = (lin & 15) * 4;
        ushort4 o;
        o.x = (unsigned short)f2bs(T[kc][nr]);
        o.y = (unsigned short)f2bs(T[kc + 1][nr]);
        o.z = (unsigned short)f2bs(T[kc + 2][nr]);
        o.w = (unsigned short)f2bs(T[kc + 3][nr]);
        *(ushort4*)&WpT[(size_t)(n0 + nr) * E_ + k0 + kc] = o;
    }
}

// ---------------------------------------------------------------------------
// Fused QKV projection, 32x32x16 MFMA. Block 128 rows x 192 cols (one head),
// wave 64x96 (2x3 frag32). A-fragments DIRECT from bf16 x (row-major = frag
// layout); W via shared LDS slabs with register prefetch. BK=64.
// ---------------------------------------------------------------------------
__global__ __launch_bounds__(256, 2) void qkv_fused(
    const short* __restrict__ xb, const short* __restrict__ WT,
    const float* __restrict__ bq, const float* __restrict__ bk,
    const float* __restrict__ bv,
    short* __restrict__ Qw, short* __restrict__ Kw, short* __restrict__ VTw)
{
    const int h = blockIdx.y;
    const int m0 = blockIdx.x * 128;
    __shared__ short Ws[8 * WSLAB];               // 24.7 KB (also V-retile buffer)

    const int tid = threadIdx.x;
    const int lane = tid & 63, w = tid >> 6;
    const int wm = w & 1, wn = w >> 1;
    const int l31 = lane & 31, hi = lane >> 5;
    const int cc = tid & 7, r8 = tid >> 3;

    f32x16 acc[2][3];
    #pragma unroll
    for (int mf = 0; mf < 2; ++mf)
        #pragma unroll
        for (int nf = 0; nf < 3; ++nf)
            #pragma unroll
            for (int i = 0; i < 16; ++i) acc[mf][nf][i] = 0.f;

    bf16x8 wr[6];
    #pragma unroll
    for (int it = 0; it < 6; ++it) {
        int rg = ((it >> 1) * 16 + h) * 64 + (it & 1) * 32 + r8;
        wr[it] = *(const bf16x8*)&WT[(size_t)rg * E_ + cc * 8];
    }

    const short* ar0 = &xb[(size_t)(m0 + wm * 64 + l31) * E_ + hi * 8];
    const short* ar1 = ar0 + (size_t)32 * E_;

    for (int k0 = 0; k0 < E_; k0 += 64) {
        #pragma unroll
        for (int it = 0; it < 6; ++it)
            *(bf16x8*)&Ws[cc * WSLAB + (it * 32 + r8) * 8] = wr[it];
        __syncthreads();
        if (k0 + 64 < E_) {
            #pragma unroll
            for (int it = 0; it < 6; ++it) {
                int rg = ((it >> 1) * 16 + h) * 64 + (it & 1) * 32 + r8;
                wr[it] = *(const bf16x8*)&WT[(size_t)rg * E_ + k0 + 64 + cc * 8];
            }
        }
        // A fragments direct from global (16 B each, frag-exact)
        bf16x8 a[2][4];
        #pragma unroll
        for (int ks = 0; ks < 4; ++ks) {
            a[0][ks] = *(const bf16x8*)&ar0[k0 + ks * 16];
            a[1][ks] = *(const bf16x8*)&ar1[k0 + ks * 16];
        }
        #pragma unroll
        for (int ks = 0; ks < 4; ++ks) {
            const int ccr = ks * 2 + hi;
            bf16x8 b[3];
            #pragma unroll
            for (int nf = 0; nf < 3; ++nf)
                b[nf] = *(const bf16x8*)&Ws[ccr * WSLAB + (wn * 96 + nf * 32 + l31) * 8];
            #pragma unroll
            for (int mf = 0; mf < 2; ++mf)
                #pragma unroll
                for (int nf = 0; nf < 3; ++nf)
                    acc[mf][nf] = mfma32(a[mf][ks], b[nf], acc[mf][nf]);
        }
        __syncthreads();
    }

    // epilogue. C/D 32-shape: col=l31, row=(reg&3)+8*(reg>>2)+4*hi
    const int bb = m0 >> 11;
    const int s0 = m0 & (S_ - 1);
    const size_t qkbase = ((size_t)bb * H_ + h) * S_;
    short* Vr = Ws;                                // reuse (needs 64*136 shorts)
    #pragma unroll
    for (int mf = 0; mf < 2; ++mf)
        #pragma unroll
        for (int nf = 0; nf < 3; ++nf) {
            const int ng = wn * 96 + nf * 32;      // wave-uniform
            const int mat = ng >> 6;
            const int d = (ng & 63) + l31;
            const int sl0 = wm * 64 + mf * 32 + 4 * hi;
            if (mat == 0) {
                const float bb_ = bq[h * D_ + d];
                #pragma unroll
                for (int rg = 0; rg < 16; ++rg) {
                    int s = s0 + sl0 + (rg & 3) + 8 * (rg >> 2);
                    Qw[(qkbase + s) * D_ + d] = f2bs((acc[mf][nf][rg] + bb_) * QSCALE);
                }
            } else if (mat == 1) {
                const float bb_ = bk[h * D_ + d];
                #pragma unroll
                for (int rg = 0; rg < 16; ++rg) {
                    int s = s0 + sl0 + (rg & 3) + 8 * (rg >> 2);
                    Kw[(qkbase + s) * D_ + d] = f2bs(acc[mf][nf][rg] + bb_);
                }
            } else {
                const float bb_ = bv[h * D_ + d];
                #pragma unroll
                for (int rg = 0; rg < 16; ++rg) {
                    int sl = sl0 + (rg & 3) + 8 * (rg >> 2);
                    Vr[d * 136 + sl] = f2bs(acc[mf][nf][rg] + bb_);
                }
            }
        }
    __syncthreads();
    const size_t vbase = ((size_t)bb * H_ + h) * (size_t)D_ * S_;
    const int sc = tid & 15, dr = tid >> 4;
    #pragma unroll
    for (int it = 0; it < 4; ++it) {
        int d = it * 16 + dr;
        *(bf16x8*)&VTw[vbase + (size_t)d * S_ + s0 + sc * 8] =
            *(const bf16x8*)&Vr[d * 136 + sc * 8];
    }
}

// ---------------------------------------------------------------------------
// Flash attention (proven r3/r5 version). Fixed-max softmax, paired q-tiles,
// double-buffered K/V LDS with register prefetch.
// ---------------------------------------------------------------------------
__global__ __launch_bounds__(256, 2) void attn(
    const short* __restrict__ Qw, const short* __restrict__ Kw,
    const short* __restrict__ VTw, short* __restrict__ Ow)
{
    const int jj = blockIdx.x;                    // 0..7
    const int bh = blockIdx.y;
    const int b = bh >> 4, h = bh & 15;
    const size_t kbase = ((size_t)b * H_ + h) * (size_t)S_ * D_;
    const size_t vbase = ((size_t)b * H_ + h) * (size_t)D_ * S_;

    __shared__ short Qs[128 * 72];
    __shared__ short Ks[2][64 * 72];
    __shared__ short Vt[2][64 * 72];

    const int tid = threadIdx.x;
    const int lane = tid & 63, w = tid >> 6;
    const int l15 = lane & 15, qd = lane >> 4;

    const int r0s = tid >> 3;
    const int c0s = (tid & 7) * 8;
    const int r1s = r0s + 32;

    #pragma unroll
    for (int phase = 0; phase < 2; ++phase) {
        const int qt = phase ? jj : (15 - jj);

        #pragma unroll
        for (int it = 0; it < 4; ++it) {
            int row = w * 32 + it * 8 + (lane >> 3);
            int cb = (lane & 7) * 8;
            *(bf16x8*)&Qs[row * 72 + cb] =
                *(const bf16x8*)&Qw[kbase + (size_t)(qt * 128 + row) * D_ + cb];
        }
        asm volatile("s_waitcnt lgkmcnt(0)" ::: "memory");
        bf16x8 qf[2][2];
        #pragma unroll
        for (int mi = 0; mi < 2; ++mi)
            #pragma unroll
            for (int t = 0; t < 2; ++t)
                qf[mi][t] = *(const bf16x8*)&Qs[(w * 32 + mi * 16 + l15) * 72 + t * 32 + qd * 8];

        f32x4 zero = {0.f, 0.f, 0.f, 0.f};
        f32x4 oacc[2][4];
        float lrow[2][4];
        #pragma unroll
        for (int mi = 0; mi < 2; ++mi) {
            #pragma unroll
            for (int c = 0; c < 4; ++c) oacc[mi][c] = zero;
            #pragma unroll
            for (int r = 0; r < 4; ++r) lrow[mi][r] = 0.f;
        }

        const int nkt = (qt + 1) * 2;
        bf16x8 kr0, kr1, vr0, vr1;
        kr0 = *(const bf16x8*)&Kw[kbase + (size_t)r0s * D_ + c0s];
        kr1 = *(const bf16x8*)&Kw[kbase + (size_t)r1s * D_ + c0s];
        vr0 = *(const bf16x8*)&VTw[vbase + (size_t)r0s * S_ + c0s];
        vr1 = *(const bf16x8*)&VTw[vbase + (size_t)r1s * S_ + c0s];
        *(bf16x8*)&Ks[0][r0s * 72 + c0s] = kr0;
        *(bf16x8*)&Ks[0][r1s * 72 + c0s] = kr1;
        *(bf16x8*)&Vt[0][r0s * 72 + c0s] = vr0;
        *(bf16x8*)&Vt[0][r1s * 72 + c0s] = vr1;
        __syncthreads();

        int p = 0;
        for (int kt = 0; kt < nkt; ++kt) {
            const bool pre = (kt + 1 < nkt);
            if (pre) {
                kr0 = *(const bf16x8*)&Kw[kbase + (size_t)((kt + 1) * 64 + r0s) * D_ + c0s];
                kr1 = *(const bf16x8*)&Kw[kbase + (size_t)((kt + 1) * 64 + r1s) * D_ + c0s];
                vr0 = *(const bf16x8*)&VTw[vbase + (size_t)r0s * S_ + (kt + 1) * 64 + c0s];
                vr1 = *(const bf16x8*)&VTw[vbase + (size_t)r1s * S_ + (kt + 1) * 64 + c0s];
            }
            f32x4 sc[2][4];
            #pragma unroll
            for (int mi = 0; mi < 2; ++mi)
                #pragma unroll
                for (int c = 0; c < 4; ++c) sc[mi][c] = zero;
            #pragma unroll
            for (int t = 0; t < 2; ++t)
                #pragma unroll
                for (int c = 0; c < 4; ++c) {
                    bf16x8 bk = *(const bf16x8*)&Ks[p][(c * 16 + l15) * 72 + t * 32 + qd * 8];
                    sc[0][c] = mfma16(qf[0][t], bk, sc[0][c]);
                    sc[1][c] = mfma16(qf[1][t], bk, sc[1][c]);
                }
            #pragma unroll
            for (int mi = 0; mi < 2; ++mi) {
                const int fr = qt * 128 + w * 32 + mi * 16;
                if (kt * 64 + 63 > fr) {
                    #pragma unroll
                    for (int c = 0; c < 4; ++c) {
                        int col = kt * 64 + c * 16 + l15;
                        #pragma unroll
                        for (int r = 0; r < 4; ++r)
                            if (col > fr + qd * 4 + r) sc[mi][c][r] = -1e30f;
                    }
                }
                #pragma unroll
                for (int c = 0; c < 4; ++c)
                    #pragma unroll
                    for (int r = 0; r < 4; ++r) {
                        float pv = __builtin_amdgcn_exp2f(sc[mi][c][r]);
                        lrow[mi][r] += pv;
                        Qs[(w * 32 + mi * 16 + qd * 4 + r) * 72 + c * 16 + l15] = f2bs(pv);
                    }
            }
            asm volatile("s_waitcnt lgkmcnt(0)" ::: "memory");
            #pragma unroll
            for (int t = 0; t < 2; ++t) {
                bf16x8 ap0 = *(const bf16x8*)&Qs[(w * 32 + l15) * 72 + t * 32 + qd * 8];
                bf16x8 ap1 = *(const bf16x8*)&Qs[(w * 32 + 16 + l15) * 72 + t * 32 + qd * 8];
                #pragma unroll
                for (int c = 0; c < 4; ++c) {
                    bf16x8 bv = *(const bf16x8*)&Vt[p][(c * 16 + l15) * 72 + t * 32 + qd * 8];
                    oacc[0][c] = mfma16(ap0, bv, oacc[0][c]);
                    oacc[1][c] = mfma16(ap1, bv, oacc[1][c]);
                }
            }
            if (pre) {
                *(bf16x8*)&Ks[1 - p][r0s * 72 + c0s] = kr0;
                *(bf16x8*)&Ks[1 - p][r1s * 72 + c0s] = kr1;
                *(bf16x8*)&Vt[1 - p][r0s * 72 + c0s] = vr0;
                *(bf16x8*)&Vt[1 - p][r1s * 72 + c0s] = vr1;
            }
            __syncthreads();
            p ^= 1;
        }

        #pragma unroll
        for (int mi = 0; mi < 2; ++mi) {
            float inv[4];
            #pragma unroll
            for (int r = 0; r < 4; ++r) {
                float l = lrow[mi][r];
                l += __shfl_xor(l, 1);
                l += __shfl_xor(l, 2);
                l += __shfl_xor(l, 4);
                l += __shfl_xor(l, 8);
                inv[r] = 1.f / l;
            }
            #pragma unroll
            for (int c = 0; c < 4; ++c)
                #pragma unroll
                for (int r = 0; r < 4; ++r) {
                    int s = qt * 128 + w * 32 + mi * 16 + qd * 4 + r;
                    Ow[((size_t)b * S_ + s) * (H_ * D_) + h * D_ + c * 16 + l15] =
                        f2bs(oacc[mi][c][r] * inv[r]);
                }
        }
    }
}

// ---------------------------------------------------------------------------
// Output projection, 32x32x16 MFMA. Block 128x128, wave 64x64 (2x2 frag32).
// A direct from global (Ow bf16 row-major); B via LDS slabs + reg prefetch.
// ---------------------------------------------------------------------------
__global__ __launch_bounds__(256, 2) void out_proj(
    const short* __restrict__ Oin, const short* __restrict__ WpT,
    const float* __restrict__ bp, float* __restrict__ out)
{
    const int m0 = blockIdx.x * 128;
    const int n0 = blockIdx.y * 128;
    __shared__ short Bs[8 * BSLAB];               // 16.5 KB

    const int tid = threadIdx.x;
    const int lane = tid & 63, w = tid >> 6;
    const int wm = w & 1, wn = w >> 1;
    const int l31 = lane & 31, hi = lane >> 5;
    const int cc = tid & 7, r8 = tid >> 3;

    f32x16 acc[2][2];
    #pragma unroll
    for (int mf = 0; mf < 2; ++mf)
        #pragma unroll
        for (int nf = 0; nf < 2; ++nf)
            #pragma unroll
            for (int i = 0; i < 16; ++i) acc[mf][nf][i] = 0.f;

    bf16x8 br[4];
    #pragma unroll
    for (int it = 0; it < 4; ++it)
        br[it] = *(const bf16x8*)&WpT[(size_t)(n0 + it * 32 + r8) * E_ + cc * 8];

    const short* ar0 = &Oin[(size_t)(m0 + wm * 64 + l31) * E_ + hi * 8];
    const short* ar1 = ar0 + (size_t)32 * E_;

    for (int k0 = 0; k0 < E_; k0 += 64) {
        #pragma unroll
        for (int it = 0; it < 4; ++it)
            *(bf16x8*)&Bs[cc * BSLAB + (it * 32 + r8) * 8] = br[it];
        __syncthreads();
        if (k0 + 64 < E_) {
            #pragma unroll
            for (int it = 0; it < 4; ++it)
                br[it] = *(const bf16x8*)&WpT[(size_t)(n0 + it * 32 + r8) * E_ + k0 + 64 + cc * 8];
        }
        bf16x8 a[2][4];
        #pragma unroll
        for (int ks = 0; ks < 4; ++ks) {
            a[0][ks] = *(const bf16x8*)&ar0[k0 + ks * 16];
            a[1][ks] = *(const bf16x8*)&ar1[k0 + ks * 16];
        }
        #pragma unroll
        for (int ks = 0; ks < 4; ++ks) {
            const int ccr = ks * 2 + hi;
            bf16x8 b[2];
            #pragma unroll
            for (int nf = 0; nf < 2; ++nf)
                b[nf] = *(const bf16x8*)&Bs[ccr * BSLAB + (wn * 64 + nf * 32 + l31) * 8];
            #pragma unroll
            for (int mf = 0; mf < 2; ++mf)
                #pragma unroll
                for (int nf = 0; nf < 2; ++nf)
                    acc[mf][nf] = mfma32(a[mf][ks], b[nf], acc[mf][nf]);
        }
        __syncthreads();
    }
    #pragma unroll
    for (int mf = 0; mf < 2; ++mf)
        #pragma unroll
        for (int nf = 0; nf < 2; ++nf) {
            const int n = n0 + wn * 64 + nf * 32 + l31;
            const float bpv = bp[n];
            const int sl0 = wm * 64 + mf * 32 + 4 * hi;
            #pragma unroll
            for (int rg = 0; rg < 16; ++rg) {
                int m = m0 + sl0 + (rg & 3) + 8 * (rg >> 2);
                out[(size_t)m * E_ + n] = acc[mf][nf][rg] + bpv;
            }
        }
}

// ---------------------------------------------------------------------------
extern "C" void kernel_launch(void* const* d_in, const int* in_sizes, int n_in,
                              void* d_out, int out_size, void* d_ws, size_t ws_size,
                              hipStream_t stream)
{
    const float* x  = (const float*)d_in[0];
    const float* Wq = (const float*)d_in[1];
    const float* bq = (const float*)d_in[2];
    const float* Wk = (const float*)d_in[3];
    const float* bk = (const float*)d_in[4];
    const float* Wv = (const float*)d_in[5];
    const float* bv = (const float*)d_in[6];
    const float* Wp = (const float*)d_in[7];
    const float* bp = (const float*)d_in[8];
    float* out = (float*)d_out;

    const size_t nQKV = (size_t)B_ * H_ * S_ * D_;   // 8,388,608 bf16 elements
    short* Qw   = (short*)d_ws;          // [B,H,S,D]; later reused for WpT
    short* Kw   = Qw + nQKV;             // [B,H,S,D]
    short* VTw  = Kw + nQKV;             // [B,H,D,S]
    short* buf3 = VTw + nQKV;            // xb (conv_x->qkv), then Ow (attn->out_proj)
    short* xbuf = buf3;                  // x as bf16 [B*S, E]
    short* Ow   = buf3;                  // [B,S,H*D]
    short* WT   = (short*)d_out;         // scratch: WT[48][64][1024], dead pre-out_proj
    short* WpT  = Qw;                    // Qw dead after attn

    conv_x<<<dim3(4096), 256, 0, stream>>>(x, xbuf);
    conv_wqkv<<<dim3(768), 256, 0, stream>>>(Wq, Wk, Wv, WT);
    qkv_fused<<<dim3(64, 16), 256, 0, stream>>>(xbuf, WT, bq, bk, bv, Qw, Kw, VTw);
    attn<<<dim3(8, 64), 256, 0, stream>>>(Qw, Kw, VTw, Ow);
    conv_wp<<<dim3(256), 256, 0, stream>>>(Wp, WpT);
    out_proj<<<dim3(64, 8), 256, 0, stream>>>(Ow, WpT, bp, out);
}